// Round 5
// baseline (286.245 us; speedup 1.0000x reference)
//
#include <hip/hip_runtime.h>

// CORN loss: logits [B, K-1] fp32, targets [B] int (1..K), out = mean loss (fp32 scalar)
// B = 4194304, K = 10 -> 9 logits/row, 37,748,736 terms = 9,437,184 float4s.
// loss(x, bt) = -log(sigmoid(bt ? x : -x) + 1e-7) ~= log(1 + exp(bt ? -x : x))
// Log batching: sum_k log(1+e^sk) = log prod_k (1+e^sk), groups of 4
// (prod < (1+e^22)^4 < fp32 max; normal logits |x| <~ 6 -> no overflow).
//
// Fused single pass + ticket finalize. Counter is hipMemsetAsync'd to 0 each
// call (round-4 lesson: "t % BLOCKS" picks a MID-dispatch block unless the
// counter starts at 0 -> ~600 unwritten partials, absmax 0.117).

#define BATCH 4194304
#define KM1   9

constexpr int THREADS = 256;
constexpr int F4T     = 8;
constexpr unsigned TOTAL_F4 = (unsigned)BATCH * KM1 / 4;    // 9,437,184
constexpr int BLOCKS = TOTAL_F4 / (THREADS * F4T);          // 4608

typedef __attribute__((ext_vector_type(4))) float f32x4;

__global__ __launch_bounds__(THREADS) void corn_fused_kernel(
    const float* __restrict__ logits,
    const int*   __restrict__ targets,
    float*       __restrict__ out,
    float*       __restrict__ partials,
    unsigned*    __restrict__ counter) {

    const unsigned q0 = blockIdx.x * (unsigned)(THREADS * F4T) + threadIdx.x;

    // 8 coalesced loads issued up-front (lane stride 16 B -> 4 KB/instruction)
    f32x4 v[F4T];
    #pragma unroll
    for (int j = 0; j < F4T; ++j)
        v[j] = reinterpret_cast<const f32x4*>(logits)[q0 + j * THREADS];

    // Per-float4 row/rank bookkeeping (targets near-coalesced, L1/L2-served)
    int rk0[F4T], rk1[F4T], kk0[F4T];
    #pragma unroll
    for (int j = 0; j < F4T; ++j) {
        const unsigned e0  = (q0 + j * THREADS) * 4u;
        const unsigned row = e0 / 9u;                       // magic-mul div
        kk0[j] = (int)(e0 - 9u * row);
        const unsigned r1  = (row + 1u < BATCH) ? row + 1u : (BATCH - 1u);
        rk0[j] = targets[row] - 1;
        rk1[j] = targets[r1]  - 1;
    }

    float acc = 0.0f;
    #pragma unroll
    for (int j = 0; j < F4T; ++j) {
        const float* f = reinterpret_cast<const float*>(&v[j]);
        float prod = 1.0f;
        #pragma unroll
        for (int c = 0; c < 4; ++c) {
            const int  k  = kk0[j] + c;
            const bool nx = (k >= 9);
            const int  kk = nx ? k - 9 : k;
            const int  rk = nx ? rk1[j] : rk0[j];
            const float x = f[c];
            const float s = (kk < rk) ? -x : x;   // bt=1 -> e^-x, bt=0 -> e^x
            prod *= 1.0f + __expf(s);             // 4 indep exps, short mul chain
        }
        acc += __logf(prod);                      // 1 log per 4 elements
    }

    // wave (64-lane) butterfly reduce
    #pragma unroll
    for (int off = 32; off > 0; off >>= 1)
        acc += __shfl_down(acc, off, 64);

    __shared__ float smem[THREADS / 64];
    __shared__ bool  last;
    if ((threadIdx.x & 63) == 0) smem[threadIdx.x >> 6] = acc;
    __syncthreads();

    if (threadIdx.x == 0) {
        const float s = smem[0] + smem[1] + smem[2] + smem[3];
        __hip_atomic_store(&partials[blockIdx.x], s,
                           __ATOMIC_RELEASE, __HIP_MEMORY_SCOPE_AGENT);
        // ACQ_REL: release our partial before the ticket; acquire all prior
        // releases if we draw the last ticket. Counter starts at 0 (memset),
        // so t == BLOCKS-1 is genuinely the final increment.
        const unsigned t = __hip_atomic_fetch_add(counter, 1u,
                           __ATOMIC_ACQ_REL, __HIP_MEMORY_SCOPE_AGENT);
        last = (t == (unsigned)(BLOCKS - 1));
    }
    __syncthreads();

    if (last) {                 // block-uniform branch
        __threadfence();        // agent fence before reading remote partials
        float a = 0.0f;
        #pragma unroll
        for (int i = 0; i < BLOCKS / THREADS; ++i)   // 18 coalesced rounds
            a += __hip_atomic_load(&partials[i * THREADS + threadIdx.x],
                                   __ATOMIC_RELAXED, __HIP_MEMORY_SCOPE_AGENT);
        #pragma unroll
        for (int off = 32; off > 0; off >>= 1)
            a += __shfl_down(a, off, 64);
        if ((threadIdx.x & 63) == 0) smem[threadIdx.x >> 6] = a;
        __syncthreads();
        if (threadIdx.x == 0) {
            const float inv_n = 1.0f / 37748736.0f;  // 1/(B*(K-1))
            out[0] = (smem[0] + smem[1] + smem[2] + smem[3]) * inv_n;
        }
    }
}

extern "C" void kernel_launch(void* const* d_in, const int* in_sizes, int n_in,
                              void* d_out, int out_size, void* d_ws, size_t ws_size,
                              hipStream_t stream) {
    const float* logits   = (const float*)d_in[0];
    const int*   targets  = (const int*)d_in[1];
    float*       out      = (float*)d_out;
    float*       partials = (float*)d_ws;                          // 4608 floats
    unsigned*    counter  = (unsigned*)((char*)d_ws + BLOCKS * 4); // 1 uint after

    // Ticket counter MUST start at 0 each call (see round-4 post-mortem).
    // hipMemsetAsync is stream-ordered and graph-capturable (harness uses it).
    hipMemsetAsync(counter, 0, sizeof(unsigned), stream);
    corn_fused_kernel<<<BLOCKS, THREADS, 0, stream>>>(logits, targets, out,
                                                      partials, counter);
}

// Round 6
// 32.415 us; speedup vs baseline: 8.8305x; 8.8305x over previous
//
#include <hip/hip_runtime.h>

// CORN loss: logits [B, K-1] fp32, targets [B] int (1..K), out = mean loss (fp32 scalar)
// B = 4194304, K = 10 -> 9 logits/row, 37,748,736 terms = 9,437,184 float4s.
// loss(x, bt) = -log(sigmoid(bt ? x : -x) + 1e-7) ~= log(1 + exp(bt ? -x : x))
// Log batching: sum_k log(1+e^sk) = log prod_k (1+e^sk) per float4
// (prod < (1+e^22)^4 < fp32 max; normal logits |x| <~ 6 -> no overflow).
//
// Round-5 post-mortem: fused ticket version ran 445 us -- per-block agent-scope
// RMW atomics emit buffer_wbl2 + buffer_inv (full L2 writeback+invalidate) per
// block, and VGPR=36 showed the compiler serialized the 8 in-flight loads.
// Reverted to the proven round-3 two-kernel structure (33.6 us), keeping only
// the log-batching delta. NO device atomics anywhere.

#define BATCH    4194304
#define KM1      9

constexpr int THREADS = 256;
constexpr int F4_PER_THREAD = 4;
constexpr int BLOCKS = (BATCH * KM1 / 4) / (THREADS * F4_PER_THREAD);  // 9216

typedef __attribute__((ext_vector_type(4))) float f32x4;

__global__ __launch_bounds__(THREADS) void corn_partial_kernel(
    const float* __restrict__ logits,
    const int*   __restrict__ targets,
    float*       __restrict__ partials) {
    const unsigned q0 = blockIdx.x * (THREADS * F4_PER_THREAD) + threadIdx.x;

    // 4 coalesced logits loads issued up-front (lane stride 16 B -> 4 KB/wave-instr)
    f32x4 v[F4_PER_THREAD];
    #pragma unroll
    for (int j = 0; j < F4_PER_THREAD; ++j)
        v[j] = reinterpret_cast<const f32x4*>(logits)[q0 + j * THREADS];

    // Per-float4 row/rank bookkeeping (targets near-coalesced, L1/L2-served)
    int rk0[F4_PER_THREAD], rk1[F4_PER_THREAD], kk0[F4_PER_THREAD];
    #pragma unroll
    for (int j = 0; j < F4_PER_THREAD; ++j) {
        const unsigned e0  = (q0 + j * THREADS) * 4u;
        const unsigned row = e0 / 9u;                   // magic-mul div
        kk0[j] = (int)(e0 - 9u * row);
        const unsigned r1 = (row + 1u < BATCH) ? row + 1u : (BATCH - 1u);
        rk0[j] = targets[row] - 1;
        rk1[j] = targets[r1]  - 1;
    }

    float acc = 0.0f;
    #pragma unroll
    for (int j = 0; j < F4_PER_THREAD; ++j) {
        const float* f = reinterpret_cast<const float*>(&v[j]);
        float prod = 1.0f;
        #pragma unroll
        for (int c = 0; c < 4; ++c) {
            const int  k  = kk0[j] + c;
            const bool nx = (k >= 9);
            const int  kk = nx ? k - 9 : k;
            const int  rk = nx ? rk1[j] : rk0[j];
            const float x = f[c];
            const float s = (kk < rk) ? -x : x;   // bt=1 -> e^-x, bt=0 -> e^x
            prod *= 1.0f + __expf(s);             // 4 indep exps, short mul chain
        }
        acc += __logf(prod);                      // 1 log per 4 elements
    }

    // wave (64-lane) butterfly reduce
    #pragma unroll
    for (int off = 32; off > 0; off >>= 1)
        acc += __shfl_down(acc, off, 64);

    __shared__ float smem[THREADS / 64];
    if ((threadIdx.x & 63) == 0) smem[threadIdx.x >> 6] = acc;
    __syncthreads();
    if (threadIdx.x == 0)
        partials[blockIdx.x] = smem[0] + smem[1] + smem[2] + smem[3];
}

__global__ __launch_bounds__(256) void corn_final_kernel(
    const float* __restrict__ partials,
    float*       __restrict__ out) {
    float acc = 0.0f;
    #pragma unroll
    for (int i = 0; i < BLOCKS / 256; ++i)       // 36 coalesced reads/thread
        acc += partials[i * 256 + threadIdx.x];

    #pragma unroll
    for (int off = 32; off > 0; off >>= 1)
        acc += __shfl_down(acc, off, 64);

    __shared__ float smem[4];
    if ((threadIdx.x & 63) == 0) smem[threadIdx.x >> 6] = acc;
    __syncthreads();
    if (threadIdx.x == 0) {
        const float inv_n = 1.0f / 37748736.0f;  // 1/(B*(K-1)), exact
        out[0] = (smem[0] + smem[1] + smem[2] + smem[3]) * inv_n;
    }
}

extern "C" void kernel_launch(void* const* d_in, const int* in_sizes, int n_in,
                              void* d_out, int out_size, void* d_ws, size_t ws_size,
                              hipStream_t stream) {
    const float* logits   = (const float*)d_in[0];
    const int*   targets  = (const int*)d_in[1];
    float*       out      = (float*)d_out;
    float*       partials = (float*)d_ws;  // 9216 floats = 36 KB scratch

    corn_partial_kernel<<<BLOCKS, THREADS, 0, stream>>>(logits, targets, partials);
    corn_final_kernel<<<1, 256, 0, stream>>>(partials, out);
}